// Round 1
// baseline (478.715 us; speedup 1.0000x reference)
//
#include <hip/hip_runtime.h>
#include <stdint.h>

#define N_TOKENS 4096
#define D_MODEL  1024
#define NUM_EXP  64
#define CAP      512

typedef unsigned short u16;
typedef __bf16 bf16x8 __attribute__((ext_vector_type(8)));
typedef float  f32x4  __attribute__((ext_vector_type(4)));
typedef const __attribute__((address_space(1))) void* as1cvp;
typedef __attribute__((address_space(3))) void*       as3vp;

__device__ __forceinline__ uint32_t f2bf_bits(float f) {
  union { float f; uint32_t u; } c; c.f = f;
  uint32_t u = c.u;
  u += 0x7fffu + ((u >> 16) & 1u);   // RNE
  return u >> 16;
}

// ---------------- Kernel 1: fp32 gate GEMM, split-K, + x->bf16 conversion ----------------
// grid (4 kslices, 64 token-groups), 256 threads. Computes part[ks][token][expert].
__global__ __launch_bounds__(256) void gate_partial_kernel(
    const float* __restrict__ x, const float* __restrict__ gw,
    float* __restrict__ part, u16* __restrict__ xb)
{
  const int ks  = blockIdx.x;        // K slice (256 wide)
  const int m0  = blockIdx.y * 64;   // token base
  const int tid = threadIdx.x;
  const int ty = tid >> 4, tx = tid & 15;
  __shared__ float4 As[64][16];      // 64 tokens x 64 K (f32), XOR-swizzled chunks
  __shared__ float4 Bs[64][16];      // 64 experts x 64 K
  float acc[4][4] = {};
  for (int kt = 0; kt < 4; ++kt) {
    const int k0 = ks * 256 + kt * 64;
    __syncthreads();
    #pragma unroll
    for (int i = 0; i < 4; ++i) {
      int idx = tid + i * 256;
      int r = idx >> 4, c = idx & 15;
      float4 v = *(const float4*)&x[(size_t)(m0 + r) * D_MODEL + k0 + c * 4];
      As[r][c ^ (r >> 2)] = v;
      uint32_t lo = f2bf_bits(v.x) | (f2bf_bits(v.y) << 16);
      uint32_t hi = f2bf_bits(v.z) | (f2bf_bits(v.w) << 16);
      *(uint2*)&xb[(size_t)(m0 + r) * D_MODEL + k0 + c * 4] = make_uint2(lo, hi);
      float4 w = *(const float4*)&gw[(size_t)r * D_MODEL + k0 + c * 4];
      Bs[r][c ^ (r >> 2)] = w;
    }
    __syncthreads();
    #pragma unroll
    for (int kk = 0; kk < 16; ++kk) {
      float4 a[4], b[4];
      #pragma unroll
      for (int j = 0; j < 4; ++j) a[j] = As[ty * 4 + j][kk ^ ty];   // broadcast within 16-lane grp
      #pragma unroll
      for (int j = 0; j < 4; ++j) b[j] = Bs[tx * 4 + j][kk ^ tx];   // conflict-free
      #pragma unroll
      for (int j = 0; j < 4; ++j)
        #pragma unroll
        for (int i2 = 0; i2 < 4; ++i2) {
          acc[j][i2] += a[j].x * b[i2].x;
          acc[j][i2] += a[j].y * b[i2].y;
          acc[j][i2] += a[j].z * b[i2].z;
          acc[j][i2] += a[j].w * b[i2].w;
        }
    }
  }
  #pragma unroll
  for (int j = 0; j < 4; ++j) {
    float4 o = make_float4(acc[j][0], acc[j][1], acc[j][2], acc[j][3]);
    size_t t = (size_t)m0 + ty * 4 + j;
    *(float4*)&part[((size_t)ks * N_TOKENS + t) * NUM_EXP + tx * 4] = o;
  }
}

// ---------------- Kernel 2: deterministic reduce + top-2 + softmax + dispatch ----------------
__global__ __launch_bounds__(256) void topk_dispatch_kernel(
    const float* __restrict__ part, int* __restrict__ cnt,
    int* __restrict__ tok, float* __restrict__ wts, int* __restrict__ dst)
{
  const int t = blockIdx.x * 256 + threadIdx.x;
  float l[64];
  const float4* p4 = (const float4*)part;
  #pragma unroll
  for (int c = 0; c < 16; ++c) {
    float4 v = p4[(size_t)t * 16 + c];
    l[c*4+0] = v.x; l[c*4+1] = v.y; l[c*4+2] = v.z; l[c*4+3] = v.w;
  }
  #pragma unroll
  for (int s = 1; s < 4; ++s) {        // fixed order -> deterministic fp32 sum
    #pragma unroll
    for (int c = 0; c < 16; ++c) {
      float4 v = p4[((size_t)s * N_TOKENS + t) * 16 + c];
      l[c*4+0] += v.x; l[c*4+1] += v.y; l[c*4+2] += v.z; l[c*4+3] += v.w;
    }
  }
  float b1 = -3.4e38f; int e1 = 0;
  #pragma unroll
  for (int e = 0; e < 64; ++e) { if (l[e] > b1) { b1 = l[e]; e1 = e; } }   // ties -> lowest idx
  float b2 = -3.4e38f; int e2 = 0;
  #pragma unroll
  for (int e = 0; e < 64; ++e) { if (e != e1 && l[e] > b2) { b2 = l[e]; e2 = e; } }
  float ex = expf(b2 - b1);
  float w1 = 1.0f / (1.0f + ex);
  float w2 = ex   / (1.0f + ex);
  int p = atomicAdd(&cnt[e1], 1);
  if (p < CAP) { tok[e1*CAP+p] = t; wts[e1*CAP+p] = w1; dst[e1*CAP+p] = 2*t; }
  p = atomicAdd(&cnt[e2], 1);
  if (p < CAP) { tok[e2*CAP+p] = t; wts[e2*CAP+p] = w2; dst[e2*CAP+p] = 2*t+1; }
}

// ---------------- Kernel 3: per-expert GEMM, bf16 MFMA ----------------
// grid (16 n-tiles, 2 m-tiles, 64 experts), 256 threads (4 waves).
// Tile: M=256 (token slots) x N=64 (out features) x K-step 64.
__global__ __launch_bounds__(256, 3) void expert_gemm_kernel(
    const u16* __restrict__ xb, const float* __restrict__ ew,
    const int* __restrict__ cnt, const int* __restrict__ tok,
    const float* __restrict__ wts, const int* __restrict__ dst,
    float* __restrict__ ybuf)
{
  const int e = blockIdx.z;
  int ne = cnt[e]; ne = ne > CAP ? CAP : ne;
  const int m0 = blockIdx.y * 256;
  if (m0 >= ne) return;
  const int n0 = blockIdx.x * 64;
  const int tid = threadIdx.x;
  const int wid = tid >> 6, lane = tid & 63;

  __shared__ u16  Alds[256 * 64];   // 32 KB bf16, rows of 128B, XOR(row&7) chunk swizzle
  __shared__ u16  Blds[64 * 64];    // 8 KB
  __shared__ int   tokL[256];
  __shared__ float wL[256];
  __shared__ int   dL[256];

  {
    int g = m0 + tid;
    bool v = g < ne;
    tokL[tid] = v ? tok[e * CAP + g] : 0;   // pad rows read token 0 (finite, discarded)
    wL[tid]   = v ? wts[e * CAP + g] : 0.f;
    dL[tid]   = v ? dst[e * CAP + g] : 0;
  }
  __syncthreads();

  // per-thread A-staging source rows fixed across K steps; source pre-swizzled so
  // linear global_load_lds dest + XOR'd read line up (both-sides-or-neither rule)
  const u16* asrc[8];
  #pragma unroll
  for (int i = 0; i < 8; ++i) {
    int idx = tid + i * 256;
    int r = idx >> 3, c = idx & 7;
    int cs = c ^ (r & 7);
    asrc[i] = xb + (size_t)tokL[r] * D_MODEL + cs * 8;
  }
  const float* Wb = ew + (size_t)e * D_MODEL * D_MODEL + (size_t)n0 * D_MODEL;

  f32x4 acc[4][4] = {};

  for (int k0 = 0; k0 < D_MODEL; k0 += 64) {
    __syncthreads();
    #pragma unroll
    for (int i = 0; i < 8; ++i) {
      int idx = tid + i * 256;
      __builtin_amdgcn_global_load_lds((as1cvp)(asrc[i] + k0),
                                       (as3vp)(Alds + idx * 8), 16, 0, 0);
    }
    #pragma unroll
    for (int i = 0; i < 4; ++i) {     // B: fp32 W -> bf16, swizzled ds_write
      int idx = tid + i * 256;
      int r = idx >> 4, c = idx & 15;
      float4 v = *(const float4*)&Wb[(size_t)r * D_MODEL + k0 + c * 4];
      uint32_t lo = f2bf_bits(v.x) | (f2bf_bits(v.y) << 16);
      uint32_t hi = f2bf_bits(v.z) | (f2bf_bits(v.w) << 16);
      int boff = r * 128 + (((c >> 1) ^ (r & 7)) << 4) + (c & 1) * 8;
      *(uint2*)((char*)Blds + boff) = make_uint2(lo, hi);
    }
    __syncthreads();
    #pragma unroll
    for (int kk = 0; kk < 2; ++kk) {
      const int kbyte = kk * 64 + (lane >> 4) * 16;
      bf16x8 a[4], b[4];
      #pragma unroll
      for (int mi = 0; mi < 4; ++mi) {
        int r = wid * 64 + mi * 16 + (lane & 15);
        a[mi] = *(const bf16x8*)((const char*)Alds + r * 128 + (kbyte ^ ((r & 7) << 4)));
      }
      #pragma unroll
      for (int nj = 0; nj < 4; ++nj) {
        int r = nj * 16 + (lane & 15);
        b[nj] = *(const bf16x8*)((const char*)Blds + r * 128 + (kbyte ^ ((r & 7) << 4)));
      }
      #pragma unroll
      for (int mi = 0; mi < 4; ++mi)
        #pragma unroll
        for (int nj = 0; nj < 4; ++nj)
          acc[mi][nj] = __builtin_amdgcn_mfma_f32_16x16x32_bf16(a[mi], b[nj], acc[mi][nj], 0, 0, 0);
    }
  }

  // epilogue: scale by gate weight, scatter rows to ybuf[dest_slot]
  #pragma unroll
  for (int mi = 0; mi < 4; ++mi) {
    #pragma unroll
    for (int r4 = 0; r4 < 4; ++r4) {
      int rl = wid * 64 + mi * 16 + (lane >> 4) * 4 + r4;  // C/D: col=lane&15, row=(lane>>4)*4+reg
      if (m0 + rl < ne) {
        float wg = wL[rl];
        size_t dbase = (size_t)dL[rl] * D_MODEL + n0 + (lane & 15);
        #pragma unroll
        for (int nj = 0; nj < 4; ++nj)
          ybuf[dbase + nj * 16] = acc[mi][nj][r4] * wg;
      }
    }
  }
}

// ---------------- Kernel 4: combine out[t] = ybuf[2t] + ybuf[2t+1] ----------------
__global__ __launch_bounds__(256) void combine_kernel(
    const float* __restrict__ ybuf, float* __restrict__ out)
{
  size_t i = (size_t)blockIdx.x * 256 + threadIdx.x;  // float4 index
  size_t t = i >> 8, c = i & 255;
  const float4* a4 = (const float4*)(ybuf + (2 * t) * D_MODEL);
  const float4* b4 = (const float4*)(ybuf + (2 * t + 1) * D_MODEL);
  float4 a = a4[c], b = b4[c];
  float4 o; o.x = a.x + b.x; o.y = a.y + b.y; o.z = a.z + b.z; o.w = a.w + b.w;
  ((float4*)out)[i] = o;
}

extern "C" void kernel_launch(void* const* d_in, const int* in_sizes, int n_in,
                              void* d_out, int out_size, void* d_ws, size_t ws_size,
                              hipStream_t stream) {
  const float* x  = (const float*)d_in[0];
  const float* gw = (const float*)d_in[1];
  const float* ew = (const float*)d_in[2];
  float* out = (float*)d_out;
  char* ws = (char*)d_ws;
  // workspace layout (bytes)
  int*   cnt  = (int*)(ws + 0);            // 64 ints
  int*   tok  = (int*)(ws + 1024);         // 64*512 ints
  float* wts  = (float*)(ws + 132096);     // 64*512 f32
  int*   dst  = (int*)(ws + 263168);       // 64*512 ints
  float* part = (float*)(ws + 394240);     // 4*4096*64 f32   (4 MB)
  u16*   xb   = (u16*)  (ws + 4588544);    // 4096*1024 bf16  (8 MB)
  float* ybuf = (float*)(ws + 12977152);   // 8192*1024 f32   (33.5 MB)

  hipMemsetAsync(cnt, 0, 64 * sizeof(int), stream);
  gate_partial_kernel<<<dim3(4, 64), 256, 0, stream>>>(x, gw, part, xb);
  topk_dispatch_kernel<<<16, 256, 0, stream>>>(part, cnt, tok, wts, dst);
  expert_gemm_kernel<<<dim3(16, 2, 64), 256, 0, stream>>>(xb, ew, cnt, tok, wts, dst, ybuf);
  combine_kernel<<<4096, 256, 0, stream>>>(ybuf, out);
}

// Round 2
// 468.566 us; speedup vs baseline: 1.0217x; 1.0217x over previous
//
#include <hip/hip_runtime.h>
#include <stdint.h>

#define N_TOKENS 4096
#define D_MODEL  1024
#define NUM_EXP  64
#define CAP      512
#define KSLICES  8

typedef unsigned short u16;
typedef __bf16 bf16x8 __attribute__((ext_vector_type(8)));
typedef float  f32x4  __attribute__((ext_vector_type(4)));
typedef const __attribute__((address_space(1))) void* as1cvp;
typedef __attribute__((address_space(3))) void*       as3vp;

__device__ __forceinline__ uint32_t f2bf_bits(float f) {
  union { float f; uint32_t u; } c; c.f = f;
  uint32_t u = c.u;
  u += 0x7fffu + ((u >> 16) & 1u);   // RNE
  return u >> 16;
}

// ---------------- Kernel 1: fp32 gate GEMM, split-K x8, + x->bf16 conversion ----------------
// grid (8 kslices, 64 token-groups), 256 threads. part[ks][token][expert].
__global__ __launch_bounds__(256) void gate_partial_kernel(
    const float* __restrict__ x, const float* __restrict__ gw,
    float* __restrict__ part, u16* __restrict__ xb)
{
  const int ks  = blockIdx.x;        // K slice (128 wide)
  const int m0  = blockIdx.y * 64;   // token base
  const int tid = threadIdx.x;
  const int ty = tid >> 4, tx = tid & 15;
  __shared__ float4 As[64][16];      // 64 tokens x 64 K (f32), XOR-swizzled chunks
  __shared__ float4 Bs[64][16];      // 64 experts x 64 K
  float acc[4][4] = {};
  for (int kt = 0; kt < 2; ++kt) {
    const int k0 = ks * 128 + kt * 64;
    __syncthreads();
    #pragma unroll
    for (int i = 0; i < 4; ++i) {
      int idx = tid + i * 256;
      int r = idx >> 4, c = idx & 15;
      float4 v = *(const float4*)&x[(size_t)(m0 + r) * D_MODEL + k0 + c * 4];
      As[r][c ^ (r >> 2)] = v;
      uint32_t lo = f2bf_bits(v.x) | (f2bf_bits(v.y) << 16);
      uint32_t hi = f2bf_bits(v.z) | (f2bf_bits(v.w) << 16);
      *(uint2*)&xb[(size_t)(m0 + r) * D_MODEL + k0 + c * 4] = make_uint2(lo, hi);
      float4 w = *(const float4*)&gw[(size_t)r * D_MODEL + k0 + c * 4];
      Bs[r][c ^ (r >> 2)] = w;
    }
    __syncthreads();
    #pragma unroll
    for (int kk = 0; kk < 16; ++kk) {
      float4 a[4], b[4];
      #pragma unroll
      for (int j = 0; j < 4; ++j) a[j] = As[ty * 4 + j][kk ^ ty];   // broadcast in 16-lane grp
      #pragma unroll
      for (int j = 0; j < 4; ++j) b[j] = Bs[tx * 4 + j][kk ^ tx];   // conflict-free
      #pragma unroll
      for (int j = 0; j < 4; ++j)
        #pragma unroll
        for (int i2 = 0; i2 < 4; ++i2) {
          acc[j][i2] += a[j].x * b[i2].x;
          acc[j][i2] += a[j].y * b[i2].y;
          acc[j][i2] += a[j].z * b[i2].z;
          acc[j][i2] += a[j].w * b[i2].w;
        }
    }
  }
  #pragma unroll
  for (int j = 0; j < 4; ++j) {
    float4 o = make_float4(acc[j][0], acc[j][1], acc[j][2], acc[j][3]);
    size_t t = (size_t)m0 + ty * 4 + j;
    *(float4*)&part[((size_t)ks * N_TOKENS + t) * NUM_EXP + tx * 4] = o;
  }
}

// ---------------- Kernel 2: deterministic reduce + top-2 + softmax + dispatch ----------------
__global__ __launch_bounds__(256) void topk_dispatch_kernel(
    const float* __restrict__ part, int* __restrict__ cnt,
    int* __restrict__ tok, float* __restrict__ wts, int* __restrict__ dst)
{
  const int t = blockIdx.x * 256 + threadIdx.x;
  float l[64];
  const float4* p4 = (const float4*)part;
  #pragma unroll
  for (int c = 0; c < 16; ++c) {
    float4 v = p4[(size_t)t * 16 + c];
    l[c*4+0] = v.x; l[c*4+1] = v.y; l[c*4+2] = v.z; l[c*4+3] = v.w;
  }
  #pragma unroll
  for (int s = 1; s < KSLICES; ++s) {   // fixed order -> deterministic fp32 sum
    #pragma unroll
    for (int c = 0; c < 16; ++c) {
      float4 v = p4[((size_t)s * N_TOKENS + t) * 16 + c];
      l[c*4+0] += v.x; l[c*4+1] += v.y; l[c*4+2] += v.z; l[c*4+3] += v.w;
    }
  }
  float b1 = -3.4e38f; int e1 = 0;
  #pragma unroll
  for (int e = 0; e < 64; ++e) { if (l[e] > b1) { b1 = l[e]; e1 = e; } }   // ties -> lowest idx
  float b2 = -3.4e38f; int e2 = 0;
  #pragma unroll
  for (int e = 0; e < 64; ++e) { if (e != e1 && l[e] > b2) { b2 = l[e]; e2 = e; } }
  float ex = expf(b2 - b1);
  float w1 = 1.0f / (1.0f + ex);
  float w2 = ex   / (1.0f + ex);
  int p = atomicAdd(&cnt[e1], 1);
  if (p < CAP) { tok[e1*CAP+p] = t; wts[e1*CAP+p] = w1; dst[e1*CAP+p] = 2*t; }
  p = atomicAdd(&cnt[e2], 1);
  if (p < CAP) { tok[e2*CAP+p] = t; wts[e2*CAP+p] = w2; dst[e2*CAP+p] = 2*t+1; }
}

// ---------------- Kernel 3: per-expert GEMM, bf16 MFMA ----------------
// grid (8 n-tiles, 2 m-tiles, 64 experts), 512 threads (8 waves, 4m x 2n of 64x64 wave tiles).
// Tile: M=256 (token slots) x N=128 (out features) x K-step 64.
__global__ __launch_bounds__(512) void expert_gemm_kernel(
    const u16* __restrict__ xb, const float* __restrict__ ew,
    const int* __restrict__ cnt, const int* __restrict__ tok,
    const float* __restrict__ wts, const int* __restrict__ dst,
    float* __restrict__ ybuf)
{
  const int e = blockIdx.z;
  int ne = cnt[e]; ne = ne > CAP ? CAP : ne;
  const int m0 = blockIdx.y * 256;
  if (m0 >= ne) return;
  const int n0 = blockIdx.x * 128;
  const int tid = threadIdx.x;
  const int wid = tid >> 6, lane = tid & 63;
  const int wm = wid & 3, wn = wid >> 2;

  __shared__ u16  Alds[256 * 64];   // 32 KB, rows of 128B, XOR(row&7) chunk swizzle
  __shared__ u16  Blds[128 * 64];   // 16 KB
  __shared__ int   tokL[256];
  __shared__ float wL[256];
  __shared__ int   dL[256];

  if (tid < 256) {
    int g = m0 + tid;
    bool v = g < ne;
    tokL[tid] = v ? tok[e * CAP + g] : 0;   // pad rows read token 0 (finite, discarded)
    wL[tid]   = v ? wts[e * CAP + g] : 0.f;
    dL[tid]   = v ? dst[e * CAP + g] : 0;
  }
  __syncthreads();

  // A-staging source rows fixed across K steps; source pre-swizzled so linear
  // global_load_lds dest + XOR'd read line up (both-sides-or-neither rule)
  const u16* asrc[4];
  #pragma unroll
  for (int i = 0; i < 4; ++i) {
    int idx = tid + i * 512;
    int r = idx >> 3, c = idx & 7;
    int cs = c ^ (r & 7);
    asrc[i] = xb + (size_t)tokL[r] * D_MODEL + cs * 8;
  }
  const float* Wb = ew + (size_t)e * D_MODEL * D_MODEL + (size_t)n0 * D_MODEL;

  f32x4 acc[4][4] = {};

  for (int k0 = 0; k0 < D_MODEL; k0 += 64) {
    __syncthreads();
    #pragma unroll
    for (int i = 0; i < 4; ++i)
      __builtin_amdgcn_global_load_lds((as1cvp)(asrc[i] + k0),
                                       (as3vp)(Alds + (tid + i * 512) * 8), 16, 0, 0);
    #pragma unroll
    for (int i = 0; i < 4; ++i) {     // B: fp32 W -> bf16, swizzled ds_write
      int idx = tid + i * 512;
      int r = idx >> 4, c = idx & 15;
      float4 v = *(const float4*)&Wb[(size_t)r * D_MODEL + k0 + c * 4];
      uint32_t lo = f2bf_bits(v.x) | (f2bf_bits(v.y) << 16);
      uint32_t hi = f2bf_bits(v.z) | (f2bf_bits(v.w) << 16);
      int boff = r * 128 + (((c >> 1) ^ (r & 7)) << 4) + (c & 1) * 8;
      *(uint2*)((char*)Blds + boff) = make_uint2(lo, hi);
    }
    __syncthreads();
    #pragma unroll
    for (int kk = 0; kk < 2; ++kk) {
      const int kbyte = kk * 64 + (lane >> 4) * 16;
      bf16x8 a[4], b[4];
      #pragma unroll
      for (int mi = 0; mi < 4; ++mi) {
        int r = wm * 64 + mi * 16 + (lane & 15);
        a[mi] = *(const bf16x8*)((const char*)Alds + r * 128 + (kbyte ^ ((r & 7) << 4)));
      }
      #pragma unroll
      for (int nj = 0; nj < 4; ++nj) {
        int r = wn * 64 + nj * 16 + (lane & 15);
        b[nj] = *(const bf16x8*)((const char*)Blds + r * 128 + (kbyte ^ ((r & 7) << 4)));
      }
      #pragma unroll
      for (int mi = 0; mi < 4; ++mi)
        #pragma unroll
        for (int nj = 0; nj < 4; ++nj)
          acc[mi][nj] = __builtin_amdgcn_mfma_f32_16x16x32_bf16(a[mi], b[nj], acc[mi][nj], 0, 0, 0);
    }
  }

  // epilogue: scale by gate weight, scatter rows to ybuf[dest_slot]
  #pragma unroll
  for (int mi = 0; mi < 4; ++mi) {
    #pragma unroll
    for (int r4 = 0; r4 < 4; ++r4) {
      int rl = wm * 64 + mi * 16 + (lane >> 4) * 4 + r4;  // C/D: col=lane&15, row=(lane>>4)*4+reg
      if (m0 + rl < ne) {
        float wg = wL[rl];
        size_t dbase = (size_t)dL[rl] * D_MODEL + n0 + wn * 64 + (lane & 15);
        #pragma unroll
        for (int nj = 0; nj < 4; ++nj)
          ybuf[dbase + nj * 16] = acc[mi][nj][r4] * wg;
      }
    }
  }
}

// ---------------- Kernel 4: combine out[t] = ybuf[2t] + ybuf[2t+1] ----------------
__global__ __launch_bounds__(256) void combine_kernel(
    const float* __restrict__ ybuf, float* __restrict__ out)
{
  size_t i = (size_t)blockIdx.x * 256 + threadIdx.x;  // float4 index
  size_t t = i >> 8, c = i & 255;
  const float4* a4 = (const float4*)(ybuf + (2 * t) * D_MODEL);
  const float4* b4 = (const float4*)(ybuf + (2 * t + 1) * D_MODEL);
  float4 a = a4[c], b = b4[c];
  float4 o; o.x = a.x + b.x; o.y = a.y + b.y; o.z = a.z + b.z; o.w = a.w + b.w;
  ((float4*)out)[i] = o;
}

extern "C" void kernel_launch(void* const* d_in, const int* in_sizes, int n_in,
                              void* d_out, int out_size, void* d_ws, size_t ws_size,
                              hipStream_t stream) {
  const float* x  = (const float*)d_in[0];
  const float* gw = (const float*)d_in[1];
  const float* ew = (const float*)d_in[2];
  float* out = (float*)d_out;
  char* ws = (char*)d_ws;
  // workspace layout (bytes)
  int*   cnt  = (int*)(ws + 0);            // 64 ints
  int*   tok  = (int*)(ws + 1024);         // 64*512 ints
  float* wts  = (float*)(ws + 132096);     // 64*512 f32
  int*   dst  = (int*)(ws + 263168);       // 64*512 ints
  float* part = (float*)(ws + 394240);     // 8*4096*64 f32   (8 MB)
  u16*   xb   = (u16*)  (ws + 8782848);    // 4096*1024 bf16  (8 MB)
  float* ybuf = (float*)(ws + 17171456);   // 8192*1024 f32   (33.5 MB)

  hipMemsetAsync(cnt, 0, 64 * sizeof(int), stream);
  gate_partial_kernel<<<dim3(KSLICES, 64), 256, 0, stream>>>(x, gw, part, xb);
  topk_dispatch_kernel<<<16, 256, 0, stream>>>(part, cnt, tok, wts, dst);
  expert_gemm_kernel<<<dim3(8, 2, 64), 512, 0, stream>>>(xb, ew, cnt, tok, wts, dst, ybuf);
  combine_kernel<<<4096, 256, 0, stream>>>(ybuf, out);
}